// Round 9
// baseline (8541.693 us; speedup 1.0000x reference)
//
#include <hip/hip_runtime.h>
#include <hip/hip_bf16.h>

#define NNODE  65536   // 2*B*S
#define NEDGE  524288  // 2*B*EPG
#define NGRAPH 512     // 2*B
#define EPG    1024
#define NPROP  5
#define SINKI  20

typedef __attribute__((ext_vector_type(4))) float f32x4;
typedef __attribute__((ext_vector_type(8))) _Float16 f16x8;

static __device__ __forceinline__ void split2(float v, _Float16& h, _Float16& l) {
    h = (_Float16)v;
    l = (_Float16)(v - (float)h);
}

static __device__ __forceinline__ unsigned packsplit(float v) {
    _Float16 h = (_Float16)v;
    _Float16 lo2 = (_Float16)(v - (float)h);
    union { _Float16 f; unsigned short s; } uh, ul;
    uh.f = h; ul.f = lo2;
    return (unsigned)uh.s | ((unsigned)ul.s << 16);
}

static __device__ __forceinline__ void unpack8(uint4 a, uint4 b, f16x8& h, f16x8& l) {
    union { unsigned u[4]; f16x8 v; } H, L;
    H.u[0] = (a.x & 0xffffu) | (a.y << 16);
    H.u[1] = (a.z & 0xffffu) | (a.w << 16);
    H.u[2] = (b.x & 0xffffu) | (b.y << 16);
    H.u[3] = (b.z & 0xffffu) | (b.w << 16);
    L.u[0] = (a.x >> 16) | (a.y & 0xffff0000u);
    L.u[1] = (a.z >> 16) | (a.w & 0xffff0000u);
    L.u[2] = (b.x >> 16) | (b.y & 0xffff0000u);
    L.u[3] = (b.z >> 16) | (b.w & 0xffff0000u);
    h = H.v; l = L.v;
}

// ---------------- single-layer encoder: y = x@W + b (f32 out) ----------------
template<int IN, int OUT>
__global__ void enc_kernel(const float* __restrict__ x, const float* __restrict__ W,
                           const float* __restrict__ b, float* __restrict__ y, int rows) {
    int idx = blockIdx.x * blockDim.x + threadIdx.x;
    if (idx >= rows * OUT) return;
    int r = idx / OUT, o = idx % OUT;
    const float* xr = x + (size_t)r * IN;
    float acc = b[o];
#pragma unroll
    for (int k = 0; k < IN; ++k) acc = fmaf(xr[k], W[k * OUT + o], acc);
    y[idx] = acc;
}

// ---------------- encoder emitting pre-split hi/lo f16 planes ----------------
template<int IN, int OUT>
__global__ void enc_split_kernel(const float* __restrict__ x, const float* __restrict__ W,
                                 const float* __restrict__ b,
                                 _Float16* __restrict__ yh, _Float16* __restrict__ yl, int rows) {
    int idx = blockIdx.x * blockDim.x + threadIdx.x;
    if (idx >= rows * OUT) return;
    int r = idx / OUT, o = idx % OUT;
    const float* xr = x + (size_t)r * IN;
    float acc = b[o];
#pragma unroll
    for (int k = 0; k < IN; ++k) acc = fmaf(xr[k], W[k * OUT + o], acc);
    _Float16 h, l; split2(acc, h, l);
    yh[idx] = h; yl[idx] = l;
}

// ---------------- W [K][C] f32 -> W^T hi/lo f16 planes [C][K] ----------------
__global__ void splitT_kernel(const float* __restrict__ W, _Float16* __restrict__ Wh,
                              _Float16* __restrict__ Wl, int K, int C) {
    int idx = blockIdx.x * blockDim.x + threadIdx.x;
    if (idx >= K * C) return;
    int k = idx / C, cc = idx % C;
    _Float16 h, l; split2(W[idx], h, l);
    Wh[(size_t)cc * K + k] = h;
    Wl[(size_t)cc * K + k] = l;
}

// ---------------- 2-layer MLP, f32 VALU (round-6 verified) ----------------
template<int IN1, int IN2, int HID, int OUT>
__global__ __launch_bounds__(256) void mlp2_kernel(
    const float* __restrict__ x1, const float* __restrict__ x2,
    const float* __restrict__ W1, const float* __restrict__ b1,
    const float* __restrict__ W2, const float* __restrict__ b2,
    float* __restrict__ y) {
    constexpr int IN = IN1 + IN2;
    constexpr int TR = 32;
    __shared__ float xs[TR][IN];
    __shared__ float hs[TR][HID];
    const int t = threadIdx.x;
    const int row0 = blockIdx.x * TR;

    constexpr int INQ = IN / 4;
    for (int idx = t; idx < TR * INQ; idx += 256) {
        int r = idx / INQ, k0 = (idx % INQ) * 4;
        float4 v;
        if (IN2 == 0 || k0 < IN1) v = *(const float4*)(x1 + (size_t)(row0 + r) * IN1 + k0);
        else                      v = *(const float4*)(x2 + (size_t)(row0 + r) * IN2 + (k0 - IN1));
        *(float4*)&xs[r][k0] = v;
    }
    __syncthreads();

    constexpr int HQ = HID / 4;
    for (int idx = t; idx < TR * HQ; idx += 256) {
        int r = idx / HQ, j0 = (idx % HQ) * 4;
        float a0 = b1[j0], a1 = b1[j0+1], a2 = b1[j0+2], a3 = b1[j0+3];
        const float* wp = W1 + j0;
#pragma unroll 8
        for (int k = 0; k < IN; ++k) {
            float xv = xs[r][k];
            float4 w = *(const float4*)(wp + k * HID);
            a0 = fmaf(xv, w.x, a0); a1 = fmaf(xv, w.y, a1);
            a2 = fmaf(xv, w.z, a2); a3 = fmaf(xv, w.w, a3);
        }
        *(float4*)&hs[r][j0] = make_float4(fmaxf(a0, 0.f), fmaxf(a1, 0.f),
                                           fmaxf(a2, 0.f), fmaxf(a3, 0.f));
    }
    __syncthreads();

    constexpr int OQ = OUT / 4;
    for (int idx = t; idx < TR * OQ; idx += 256) {
        int r = idx / OQ, d0 = (idx % OQ) * 4;
        float a0 = b2[d0], a1 = b2[d0+1], a2 = b2[d0+2], a3 = b2[d0+3];
        const float* wp = W2 + d0;
#pragma unroll 8
        for (int k = 0; k < HID; ++k) {
            float hv = hs[r][k];
            float4 w = *(const float4*)(wp + k * OUT);
            a0 = fmaf(hv, w.x, a0); a1 = fmaf(hv, w.y, a1);
            a2 = fmaf(hv, w.z, a2); a3 = fmaf(hv, w.w, a3);
        }
        *(float4*)(y + (size_t)(row0 + r) * OUT + d0) = make_float4(a0, a1, a2, a3);
    }
}

// ---------------- fused u-MLP + t-MLP (f32 VALU, round-6 math) ----------------
// h = relu([c||agg]@Wu1+b1)@Wu2+b2 ; tb = relu(h@Wt1+bt1)@Wt2+bt2
__global__ __launch_bounds__(256) void ut_mlp_kernel(
    const float* __restrict__ x1, const float* __restrict__ x2,
    const float* __restrict__ W1, const float* __restrict__ b1,
    const float* __restrict__ W2, const float* __restrict__ b2,
    const float* __restrict__ Wt1, const float* __restrict__ bt1,
    const float* __restrict__ Wt2, const float* __restrict__ bt2,
    float* __restrict__ y, float* __restrict__ tb) {
    constexpr int IN1 = 64, IN2 = 128, HID = 128, OUT = 64;
    constexpr int IN = IN1 + IN2;
    constexpr int TR = 32;
    __shared__ float xs[TR][IN];    // 24 KB; aliased by ho after layer-1 reads finish
    __shared__ float hs[TR][HID];   // 16 KB; aliased by th after layer-2 reads finish
    float (*ho)[OUT] = (float(*)[OUT])xs;
    float (*th)[32]  = (float(*)[32])hs;
    const int t = threadIdx.x;
    const int row0 = blockIdx.x * TR;

    constexpr int INQ = IN / 4;
    for (int idx = t; idx < TR * INQ; idx += 256) {
        int r = idx / INQ, k0 = (idx % INQ) * 4;
        float4 v;
        if (k0 < IN1) v = *(const float4*)(x1 + (size_t)(row0 + r) * IN1 + k0);
        else          v = *(const float4*)(x2 + (size_t)(row0 + r) * IN2 + (k0 - IN1));
        *(float4*)&xs[r][k0] = v;
    }
    __syncthreads();

    constexpr int HQ = HID / 4;
    for (int idx = t; idx < TR * HQ; idx += 256) {
        int r = idx / HQ, j0 = (idx % HQ) * 4;
        float a0 = b1[j0], a1 = b1[j0+1], a2 = b1[j0+2], a3 = b1[j0+3];
        const float* wp = W1 + j0;
#pragma unroll 8
        for (int k = 0; k < IN; ++k) {
            float xv = xs[r][k];
            float4 w = *(const float4*)(wp + k * HID);
            a0 = fmaf(xv, w.x, a0); a1 = fmaf(xv, w.y, a1);
            a2 = fmaf(xv, w.z, a2); a3 = fmaf(xv, w.w, a3);
        }
        *(float4*)&hs[r][j0] = make_float4(fmaxf(a0, 0.f), fmaxf(a1, 0.f),
                                           fmaxf(a2, 0.f), fmaxf(a3, 0.f));
    }
    __syncthreads();
    // layer 2: all xs reads completed before the barrier above -> ho (alias xs) safe
    constexpr int OQ = OUT / 4;
    for (int idx = t; idx < TR * OQ; idx += 256) {
        int r = idx / OQ, d0 = (idx % OQ) * 4;
        float a0 = b2[d0], a1 = b2[d0+1], a2 = b2[d0+2], a3 = b2[d0+3];
        const float* wp = W2 + d0;
#pragma unroll 8
        for (int k = 0; k < HID; ++k) {
            float hv = hs[r][k];
            float4 w = *(const float4*)(wp + k * OUT);
            a0 = fmaf(hv, w.x, a0); a1 = fmaf(hv, w.y, a1);
            a2 = fmaf(hv, w.z, a2); a3 = fmaf(hv, w.w, a3);
        }
        float4 v = make_float4(a0, a1, a2, a3);
        *(float4*)(y + (size_t)(row0 + r) * OUT + d0) = v;
        *(float4*)&ho[r][d0] = v;
    }
    __syncthreads();
    // t layer 1: hs reads completed before the barrier above -> th (alias hs) safe
    for (int idx = t; idx < TR * 8; idx += 256) {
        int r = idx >> 3, j0 = (idx & 7) * 4;
        float a0 = bt1[j0], a1 = bt1[j0+1], a2 = bt1[j0+2], a3 = bt1[j0+3];
        const float* wp = Wt1 + j0;
#pragma unroll 8
        for (int k = 0; k < 64; ++k) {
            float xv = ho[r][k];
            float4 w = *(const float4*)(wp + k * 32);
            a0 = fmaf(xv, w.x, a0); a1 = fmaf(xv, w.y, a1);
            a2 = fmaf(xv, w.z, a2); a3 = fmaf(xv, w.w, a3);
        }
        *(float4*)&th[r][j0] = make_float4(fmaxf(a0, 0.f), fmaxf(a1, 0.f),
                                           fmaxf(a2, 0.f), fmaxf(a3, 0.f));
    }
    __syncthreads();
    for (int idx = t; idx < TR * 8; idx += 256) {
        int r = idx >> 3, o0 = (idx & 7) * 4;
        float a0 = bt2[o0], a1 = bt2[o0+1], a2 = bt2[o0+2], a3 = bt2[o0+3];
        const float* wp = Wt2 + o0;
#pragma unroll
        for (int k = 0; k < 32; ++k) {
            float hv = th[r][k];
            float4 w = *(const float4*)(wp + k * 32);
            a0 = fmaf(hv, w.x, a0); a1 = fmaf(hv, w.y, a1);
            a2 = fmaf(hv, w.z, a2); a3 = fmaf(hv, w.w, a3);
        }
        *(float4*)(tb + (size_t)(row0 + r) * 32 + o0) = make_float4(a0, a1, a2, a3);
    }
}

// ---------------- per-graph message MLP (split-f16 MFMA, 16 waves) ----------------
// 1024 threads: wid 0..15 -> rg = wid>>3 (0..1, 32-row band via rf), cg = wid&7 (16-col strip).
// Math identical to the round-6-verified kernel; only the wave decomposition and
// strides change. b1 fragments register-resident; b2 fragments re-read from L2 per tile.
__global__ __launch_bounds__(1024, 1) void msg_kernel(
    const float* __restrict__ c,
    const _Float16* __restrict__ eh, const _Float16* __restrict__ el,
    const int* __restrict__ from_idx, const int* __restrict__ to_idx,
    const _Float16* __restrict__ W1h, const _Float16* __restrict__ W1l, const float* __restrict__ b1,
    const _Float16* __restrict__ W2h, const _Float16* __restrict__ W2l, const float* __restrict__ b2,
    float* __restrict__ agg) {
    __shared__ float ag[128][128];        // 64 KB, atomic column xor-swizzled
    __shared__ _Float16 csh[128 * 64];    // 16 KB
    __shared__ _Float16 csl[128 * 64];    // 16 KB
    __shared__ unsigned Hp[64 * 128];     // 32 KB packed (hi|lo<<16)
    __shared__ int ef[1024], et[1024];    // 8 KB
    const int g = blockIdx.x, t = threadIdx.x;
    const int l = t & 63, wid = t >> 6;
    const int rg = wid >> 3, cg = wid & 7;
    const int lr = l & 15, lk = (l >> 4) * 8;
    const int ebase = g * EPG, nbase = g * 128;
    const int col = cg * 16 + lr;         // this wave's 16-col strip

    // b1 fragments resident (40 VGPR)
    f16x8 b1h[5], b1l[5];
#pragma unroll
    for (int kf = 0; kf < 5; ++kf) {
        b1h[kf] = *(const f16x8*)&W1h[(size_t)col * 160 + kf * 32 + lk];
        b1l[kf] = *(const f16x8*)&W1l[(size_t)col * 160 + kf * 32 + lk];
    }
    const float b1v = b1[col];
    const float b2v = b2[col];

    // stage: zero ag, split c into hi/lo planes, local edge ids
    for (int idx = t; idx < 4096; idx += 1024)
        ((float4*)ag)[idx] = make_float4(0.f, 0.f, 0.f, 0.f);
    {
        const float* cblk = c + (size_t)nbase * 64;
        char* chB = (char*)csh; char* clB = (char*)csl;
        for (int idx = t; idx < 8192; idx += 1024) {
            int row = idx >> 6, k = idx & 63;
            _Float16 h, lo2; split2(cblk[idx], h, lo2);
            int byte = ((row << 7) | (k << 1)) ^ ((row & 7) << 4);
            *(_Float16*)(chB + byte) = h;
            *(_Float16*)(clB + byte) = lo2;
        }
    }
    for (int idx = t; idx < 1024; idx += 1024) {
        ef[idx] = from_idx[ebase + idx] - nbase;
        et[idx] = to_idx[ebase + idx] - nbase;
    }
    __syncthreads();

    char* chB = (char*)csh; char* clB = (char*)csl;

    for (int tile = 0; tile < 32; ++tile) {
        f32x4 acc[2];
        // layer 1: two 16-row fragments per wave
#pragma unroll
        for (int rf = 0; rf < 2; ++rf) {
            const int R = tile * 64 + rg * 32 + rf * 16 + lr;
            const int e2 = R >> 1, dir = R & 1;
            const int fi = ef[e2], ti = et[e2];
            const int rA = dir ? ti : fi, rB = dir ? fi : ti;
            const int swA = (rA & 7) << 4, swB = (rB & 7) << 4;
            f16x8 ah[5], al[5];
            ah[0] = *(const f16x8*)(chB + (((rA << 7) | (lk << 1)) ^ swA));
            al[0] = *(const f16x8*)(clB + (((rA << 7) | (lk << 1)) ^ swA));
            ah[1] = *(const f16x8*)(chB + (((rA << 7) | ((32 + lk) << 1)) ^ swA));
            al[1] = *(const f16x8*)(clB + (((rA << 7) | ((32 + lk) << 1)) ^ swA));
            ah[2] = *(const f16x8*)(chB + (((rB << 7) | (lk << 1)) ^ swB));
            al[2] = *(const f16x8*)(clB + (((rB << 7) | (lk << 1)) ^ swB));
            ah[3] = *(const f16x8*)(chB + (((rB << 7) | ((32 + lk) << 1)) ^ swB));
            al[3] = *(const f16x8*)(clB + (((rB << 7) | ((32 + lk) << 1)) ^ swB));
            ah[4] = *(const f16x8*)&eh[(size_t)(ebase + e2) * 32 + lk];
            al[4] = *(const f16x8*)&el[(size_t)(ebase + e2) * 32 + lk];
            acc[rf] = (f32x4){b1v, b1v, b1v, b1v};
#pragma unroll
            for (int kf = 0; kf < 5; ++kf) {
                acc[rf] = __builtin_amdgcn_mfma_f32_16x16x32_f16(ah[kf], b1h[kf], acc[rf], 0, 0, 0);
                acc[rf] = __builtin_amdgcn_mfma_f32_16x16x32_f16(al[kf], b1h[kf], acc[rf], 0, 0, 0);
                acc[rf] = __builtin_amdgcn_mfma_f32_16x16x32_f16(ah[kf], b1l[kf], acc[rf], 0, 0, 0);
            }
        }
        __syncthreads();   // prev tile's Hp reads complete
        // relu -> packed Hp (dword-xor swizzle)
#pragma unroll
        for (int rf = 0; rf < 2; ++rf)
#pragma unroll
            for (int q = 0; q < 4; ++q) {
                const int row = rg * 32 + rf * 16 + (l >> 4) * 4 + q;
                Hp[(row * 128 + col) ^ ((row & 7) << 2)] = packsplit(fmaxf(acc[rf][q], 0.f));
            }
        __syncthreads();
        // layer 2 + scatter (b2 fragments from global; L2-hot)
#pragma unroll
        for (int rf = 0; rf < 2; ++rf) {
            const int row = rg * 32 + rf * 16 + lr;
            const int sw = (row & 7) << 2;
            f32x4 acc2 = (f32x4){b2v, b2v, b2v, b2v};
#pragma unroll
            for (int kf = 0; kf < 4; ++kf) {
                const int c0 = kf * 32 + lk;
                uint4 pa = *(const uint4*)&Hp[(row * 128 + c0) ^ sw];
                uint4 pb = *(const uint4*)&Hp[(row * 128 + c0 + 4) ^ sw];
                f16x8 xh, xl; unpack8(pa, pb, xh, xl);
                f16x8 w2h = *(const f16x8*)&W2h[(size_t)col * 128 + kf * 32 + lk];
                f16x8 w2l = *(const f16x8*)&W2l[(size_t)col * 128 + kf * 32 + lk];
                acc2 = __builtin_amdgcn_mfma_f32_16x16x32_f16(xh, w2h, acc2, 0, 0, 0);
                acc2 = __builtin_amdgcn_mfma_f32_16x16x32_f16(xl, w2h, acc2, 0, 0, 0);
                acc2 = __builtin_amdgcn_mfma_f32_16x16x32_f16(xh, w2l, acc2, 0, 0, 0);
            }
            const int r0 = rg * 32 + rf * 16 + ((l >> 4) << 2);
            const int e0 = (tile * 64 + r0) >> 1;
            int dst[4] = { et[e0], ef[e0], et[e0 + 1], ef[e0 + 1] };
#pragma unroll
            for (int q = 0; q < 4; ++q)
                atomicAdd(&ag[dst[q]][col ^ ((dst[q] & 7) << 2)], acc2[q]);
        }
    }
    __syncthreads();
    float* aout = agg + (size_t)g * 128 * 128;
    for (int idx = t; idx < 4096; idx += 1024) {
        int row = idx >> 5, c4 = (idx & 31) << 2;
        ((float4*)aout)[idx] = *(const float4*)&ag[row][c4 ^ ((row & 7) << 2)];
    }
}

// ---------------- per-pair: sim -> sinkhorn -> T-apply -> store (+score) ----------------
__global__ __launch_bounds__(512) void sink_kernel(
    const float* __restrict__ tbuf, const float* __restrict__ h,
    float* __restrict__ store, float* __restrict__ scores, int do_score) {
    __shared__ float la[128][128];      // 64 KB: log_a then T
    __shared__ float ub[2 * 128 * 66];  // union: (tq,tc)[128][33] then (hq,hc)[128][66]
    __shared__ float pm[512], ps[512];
    const int p = blockIdx.x, t = threadIdx.x;
    const int w = t >> 6, l = t & 63;

    const float* tq_src = tbuf + (size_t)(2 * p)     * 128 * 32;
    const float* tc_src = tbuf + (size_t)(2 * p + 1) * 128 * 32;
    for (int idx = t; idx < 4096; idx += 512) {
        int i = idx >> 5, k = idx & 31;
        ub[i * 33 + k]            = tq_src[idx];
        ub[128 * 33 + i * 33 + k] = tc_src[idx];
    }
    __syncthreads();

    for (int idx = t; idx < 16384; idx += 512) {
        int i = idx >> 7, j = idx & 127;
        float acc = 0.f;
#pragma unroll
        for (int k = 0; k < 32; ++k)
            acc = fmaf(ub[i * 33 + k], ub[128 * 33 + j * 33 + k], acc);
        la[i][j] = acc * 10.f;   // 1/TEMP
    }
    __syncthreads();

    for (int iter = 0; iter < SINKI; ++iter) {
        for (int r = w; r < 128; r += 8) {
            float a0 = la[r][l], a1 = la[r][l + 64];
            float mx = fmaxf(a0, a1);
#pragma unroll
            for (int off = 32; off >= 1; off >>= 1) mx = fmaxf(mx, __shfl_xor(mx, off));
            float s = __expf(a0 - mx) + __expf(a1 - mx);
#pragma unroll
            for (int off = 32; off >= 1; off >>= 1) s += __shfl_xor(s, off);
            float lse = mx + __logf(s);
            la[r][l]      = a0 - lse;
            la[r][l + 64] = a1 - lse;
        }
        __syncthreads();
        const int j = t & 127, q4 = t >> 7, i0 = q4 * 32;
        float mx = -INFINITY;
        for (int i = i0; i < i0 + 32; ++i) mx = fmaxf(mx, la[i][j]);
        pm[t] = mx;
        __syncthreads();
        const float M = fmaxf(fmaxf(pm[j], pm[j + 128]), fmaxf(pm[j + 256], pm[j + 384]));
        float s = 0.f;
        for (int i = i0; i < i0 + 32; ++i) s += __expf(la[i][j] - M);
        ps[t] = s;
        __syncthreads();
        const float lse = M + __logf(ps[j] + ps[j + 128] + ps[j + 256] + ps[j + 384]);
        for (int i = i0; i < i0 + 32; ++i) la[i][j] -= lse;
        __syncthreads();
    }

    for (int idx = t; idx < 16384; idx += 512)
        ((float*)la)[idx] = __expf(((float*)la)[idx]);
    const float* hq_src = h + (size_t)(2 * p)     * 128 * 64;
    const float* hc_src = h + (size_t)(2 * p + 1) * 128 * 64;
    for (int idx = t; idx < 8192; idx += 512) {
        int i = idx >> 6, d = idx & 63;
        ub[i * 66 + d]            = hq_src[idx];
        ub[128 * 66 + i * 66 + d] = hc_src[idx];
    }
    __syncthreads();

    float sc = 0.f;
    float* store_q = store + (size_t)(2 * p)     * 128 * 64;
    float* store_c = store + (size_t)(2 * p + 1) * 128 * 64;
    for (int idx = t; idx < 8192; idx += 512) {
        int i = idx >> 6, d = idx & 63;
        float acc = 0.f;
#pragma unroll 8
        for (int j = 0; j < 128; ++j)
            acc = fmaf(la[i][j], ub[128 * 66 + j * 66 + d], acc);
        store_q[idx] = acc;
        if (do_score) sc += fmaxf(ub[i * 66 + d] - acc, 0.f);
    }
    for (int idx = t; idx < 8192; idx += 512) {
        int j = idx >> 6, d = idx & 63;
        float acc = 0.f;
#pragma unroll 8
        for (int i = 0; i < 128; ++i)
            acc = fmaf(la[i][j], ub[i * 66 + d], acc);
        store_c[idx] = acc;
    }
    if (do_score) {
#pragma unroll
        for (int off = 32; off >= 1; off >>= 1) sc += __shfl_xor(sc, off);
        if (l == 0) pm[w] = sc;
        __syncthreads();
        if (t == 0) {
            float s8 = 0.f;
#pragma unroll
            for (int i = 0; i < 8; ++i) s8 += pm[i];
            scores[p] = -s8;
        }
    }
}

extern "C" void kernel_launch(void* const* d_in, const int* in_sizes, int n_in,
                              void* d_out, int out_size, void* d_ws, size_t ws_size,
                              hipStream_t stream) {
    const float* node_features = (const float*)d_in[0];
    const float* edge_features = (const float*)d_in[1];
    const float* W_enc_n = (const float*)d_in[2];
    const float* b_enc_n = (const float*)d_in[3];
    const float* W_enc_e = (const float*)d_in[4];
    const float* b_enc_e = (const float*)d_in[5];
    const float* W_c1 = (const float*)d_in[6];
    const float* b_c1 = (const float*)d_in[7];
    const float* W_c2 = (const float*)d_in[8];
    const float* b_c2 = (const float*)d_in[9];
    const float* W_m1 = (const float*)d_in[10];
    const float* b_m1 = (const float*)d_in[11];
    const float* W_m2 = (const float*)d_in[12];
    const float* b_m2 = (const float*)d_in[13];
    const float* W_u1 = (const float*)d_in[14];
    const float* b_u1 = (const float*)d_in[15];
    const float* W_u2 = (const float*)d_in[16];
    const float* b_u2 = (const float*)d_in[17];
    const float* W_t1 = (const float*)d_in[18];
    const float* b_t1 = (const float*)d_in[19];
    const float* W_t2 = (const float*)d_in[20];
    const float* b_t2 = (const float*)d_in[21];
    const int* from_idx = (const int*)d_in[22];
    const int* to_idx   = (const int*)d_in[23];
    float* scores = (float*)d_out;

    char* ws = (char*)d_ws;
    size_t off = 0;
    auto alloc = [&](size_t bytes) { char* p = ws + off; off += (bytes + 255) & ~(size_t)255; return p; };
    float* h    = (float*)alloc((size_t)NNODE * 64 * 4);
    float* st   = (float*)alloc((size_t)NNODE * 64 * 4);
    float* cbuf = (float*)alloc((size_t)NNODE * 64 * 4);
    float* aggb = (float*)alloc((size_t)NNODE * 128 * 4);
    float* tb   = (float*)alloc((size_t)NNODE * 32 * 4);
    _Float16* eench = (_Float16*)alloc((size_t)NEDGE * 32 * 2);
    _Float16* eencl = (_Float16*)alloc((size_t)NEDGE * 32 * 2);
    _Float16* Wm1h = (_Float16*)alloc(160 * 128 * 2);
    _Float16* Wm1l = (_Float16*)alloc(160 * 128 * 2);
    _Float16* Wm2h = (_Float16*)alloc(128 * 128 * 2);
    _Float16* Wm2l = (_Float16*)alloc(128 * 128 * 2);
    (void)ws_size; (void)in_sizes; (void)n_in; (void)out_size;

    hipMemsetAsync(st, 0, (size_t)NNODE * 64 * sizeof(float), stream);
    enc_kernel<16, 64><<<(NNODE * 64 + 255) / 256, 256, 0, stream>>>(node_features, W_enc_n, b_enc_n, h, NNODE);
    enc_split_kernel<8, 32><<<(NEDGE * 32 + 255) / 256, 256, 0, stream>>>(edge_features, W_enc_e, b_enc_e, eench, eencl, NEDGE);
    splitT_kernel<<<(160 * 128 + 255) / 256, 256, 0, stream>>>(W_m1, Wm1h, Wm1l, 160, 128);
    splitT_kernel<<<(128 * 128 + 255) / 256, 256, 0, stream>>>(W_m2, Wm2h, Wm2l, 128, 128);

    for (int it = 0; it < NPROP; ++it) {
        mlp2_kernel<64, 64, 128, 64><<<NNODE / 32, 256, 0, stream>>>(h, st, W_c1, b_c1, W_c2, b_c2, cbuf);
        msg_kernel<<<NGRAPH, 1024, 0, stream>>>(
            cbuf, eench, eencl, from_idx, to_idx, Wm1h, Wm1l, b_m1, Wm2h, Wm2l, b_m2, aggb);
        ut_mlp_kernel<<<NNODE / 32, 256, 0, stream>>>(
            cbuf, aggb, W_u1, b_u1, W_u2, b_u2, W_t1, b_t1, W_t2, b_t2, h, tb);
        sink_kernel<<<256, 512, 0, stream>>>(tb, h, st, scores, it == NPROP - 1 ? 1 : 0);
    }
}